// Round 4
// baseline (382.053 us; speedup 1.0000x reference)
//
#include <hip/hip_runtime.h>
#include <math.h>

#define EPS 1e-5f

constexpr int D   = 512;
constexpr int B   = 16;
constexpr int N   = 8192;
constexpr int BPB = 128;                      // blocks per batch
constexpr int WPB = 4;                        // waves per block (256 threads)
constexpr int ROWS_PER_BLOCK = N / BPB;       // 64
constexpr int ROWS_PER_WAVE  = ROWS_PER_BLOCK / WPB; // 16
constexpr int NPART = B * BPB;                // 2048 block-partials

// ws float layout (total ~4.03 MiB):
//   [0,512)              g[d] = qn[d]*w[d]/sqrt(D)
//   [512]                c1 = sum_d g[d]
//   [1024, 1024+NPART*D) block partial accumulators (2048*512 floats)
//   then NPART*2         (M, L) per block
constexpr size_t WS_PARTIAL = 1024;
constexpr size_t WS_ML      = WS_PARTIAL + (size_t)NPART * D;

// ---------------------------------------------------------------------------
// Kernel 0: layernorm the query, fold in ln_weight and 1/sqrt(D).
// One wave; lane j owns dims {4j..4j+3, 256+4j..256+4j+3}.
// score_n = inv_n * (sum_d g[d]*x[n,d] - mu_n * c1) + const; const cancels
// in softmax (it's sum_d qn[d]*b[d], row-independent).
// ---------------------------------------------------------------------------
__global__ void prep_kernel(const float* __restrict__ q,
                            const float* __restrict__ w,
                            const float* __restrict__ bias,
                            float* __restrict__ ws) {
    const int lane = threadIdx.x & 63;
    float4 q0 = *(const float4*)(q + 4 * lane);
    float4 q1 = *(const float4*)(q + 256 + 4 * lane);

    float s  = q0.x + q0.y + q0.z + q0.w + q1.x + q1.y + q1.z + q1.w;
    float ss = q0.x*q0.x + q0.y*q0.y + q0.z*q0.z + q0.w*q0.w
             + q1.x*q1.x + q1.y*q1.y + q1.z*q1.z + q1.w*q1.w;
    #pragma unroll
    for (int m = 1; m < 64; m <<= 1) {
        s  += __shfl_xor(s,  m);
        ss += __shfl_xor(ss, m);
    }
    const float mu  = s * (1.0f / 512.0f);
    const float var = ss * (1.0f / 512.0f) - mu * mu;
    const float inv = rsqrtf(var + EPS);
    const float scale = 0.044194173824159216f;   // 1/sqrt(512)

    float4 w0 = *(const float4*)(w + 4 * lane);
    float4 w1 = *(const float4*)(w + 256 + 4 * lane);
    float4 b0 = *(const float4*)(bias + 4 * lane);
    float4 b1 = *(const float4*)(bias + 256 + 4 * lane);

    float4 g0, g1;
    g0.x = ((q0.x - mu) * inv * w0.x + b0.x) * w0.x * scale;
    g0.y = ((q0.y - mu) * inv * w0.y + b0.y) * w0.y * scale;
    g0.z = ((q0.z - mu) * inv * w0.z + b0.z) * w0.z * scale;
    g0.w = ((q0.w - mu) * inv * w0.w + b0.w) * w0.w * scale;
    g1.x = ((q1.x - mu) * inv * w1.x + b1.x) * w1.x * scale;
    g1.y = ((q1.y - mu) * inv * w1.y + b1.y) * w1.y * scale;
    g1.z = ((q1.z - mu) * inv * w1.z + b1.z) * w1.z * scale;
    g1.w = ((q1.w - mu) * inv * w1.w + b1.w) * w1.w * scale;

    float c1 = g0.x + g0.y + g0.z + g0.w + g1.x + g1.y + g1.z + g1.w;
    #pragma unroll
    for (int m = 1; m < 64; m <<= 1) c1 += __shfl_xor(c1, m);

    *(float4*)(ws + 4 * lane)       = g0;
    *(float4*)(ws + 256 + 4 * lane) = g1;
    if (lane == 0) ws[512] = c1;
}

// ---------------------------------------------------------------------------
// Kernel 1: single-pass fused LN + score + online-softmax weighted pooling.
// One wave per row (64 lanes x 8 floats = full 2KB row in registers).
// Depth-2 rotating prefetch (rows r / r+1 / r+2 live) hides HBM latency
// within a wave; 6 blocks/CU (24 waves) gives TLP on top.
// __launch_bounds__(256,6): VGPR cap 85 vs ~60 estimated live — no-spill
// margin chosen deliberately over max-occupancy (spill = scratch traffic
// on the critical path of a BW-bound kernel; 24 waves/CU already holds
// ~100KB of loads in flight vs ~2.5KB Little's-law requirement).
// ---------------------------------------------------------------------------
__global__ __launch_bounds__(256, 6)
void pool_pass1(const float* __restrict__ x,
                const float* __restrict__ ws_g,
                float* __restrict__ partial,
                float* __restrict__ ml) {
    const int tid  = threadIdx.x;
    const int lane = tid & 63;
    const int wave = tid >> 6;
    const int blk      = blockIdx.x;        // 0..B*BPB-1
    const int b        = blk >> 7;          // / BPB
    const int blk_in_b = blk & (BPB - 1);

    const float c1 = ws_g[512];
    float4 g0 = *(const float4*)(ws_g + 4 * lane);
    float4 g1 = *(const float4*)(ws_g + 256 + 4 * lane);

    const float* xrow = x + ((size_t)b * N
                           + (size_t)blk_in_b * ROWS_PER_BLOCK
                           + (size_t)wave * ROWS_PER_WAVE) * D;
    const int o0 = 4 * lane;
    const int o1 = 256 + 4 * lane;

    float m = -INFINITY, l = 0.0f;
    float4 acc0 = {0.f, 0.f, 0.f, 0.f};
    float4 acc1 = {0.f, 0.f, 0.f, 0.f};

    // rotating buffers: a = row r (consumed), b = row r+1, c = row r+2 (loading)
    float4 a0 = *(const float4*)(xrow + o0);
    float4 a1 = *(const float4*)(xrow + o1);
    float4 b0 = *(const float4*)(xrow + D + o0);
    float4 b1 = *(const float4*)(xrow + D + o1);

    #pragma unroll
    for (int r = 0; r < ROWS_PER_WAVE; ++r) {
        float4 c0 = a0, c1v = a1;               // dummy init (tail iters)
        if (r + 2 < ROWS_PER_WAVE) {
            c0  = *(const float4*)(xrow + 2 * D + o0);
            c1v = *(const float4*)(xrow + 2 * D + o1);
        }

        float s  = a0.x + a0.y + a0.z + a0.w + a1.x + a1.y + a1.z + a1.w;
        float ss = a0.x*a0.x;
        ss = fmaf(a0.y, a0.y, ss); ss = fmaf(a0.z, a0.z, ss); ss = fmaf(a0.w, a0.w, ss);
        ss = fmaf(a1.x, a1.x, ss); ss = fmaf(a1.y, a1.y, ss);
        ss = fmaf(a1.z, a1.z, ss); ss = fmaf(a1.w, a1.w, ss);
        float gd = g0.x * a0.x;
        gd = fmaf(g0.y, a0.y, gd); gd = fmaf(g0.z, a0.z, gd); gd = fmaf(g0.w, a0.w, gd);
        gd = fmaf(g1.x, a1.x, gd); gd = fmaf(g1.y, a1.y, gd);
        gd = fmaf(g1.z, a1.z, gd); gd = fmaf(g1.w, a1.w, gd);

        #pragma unroll
        for (int msk = 1; msk < 64; msk <<= 1) {
            s  += __shfl_xor(s,  msk);
            ss += __shfl_xor(ss, msk);
            gd += __shfl_xor(gd, msk);
        }

        const float mu    = s * (1.0f / 512.0f);
        const float var   = ss * (1.0f / 512.0f) - mu * mu;
        const float inv   = rsqrtf(var + EPS);
        const float score = inv * fmaf(-mu, c1, gd);   // + const, cancels in softmax

        if (score > m) {               // wave-uniform branch
            const float f = __expf(m - score);   // m=-inf on first row -> f=0
            l *= f;
            acc0.x *= f; acc0.y *= f; acc0.z *= f; acc0.w *= f;
            acc1.x *= f; acc1.y *= f; acc1.z *= f; acc1.w *= f;
            m = score;
        }
        const float p = __expf(score - m);
        l += p;
        acc0.x = fmaf(p, a0.x, acc0.x); acc0.y = fmaf(p, a0.y, acc0.y);
        acc0.z = fmaf(p, a0.z, acc0.z); acc0.w = fmaf(p, a0.w, acc0.w);
        acc1.x = fmaf(p, a1.x, acc1.x); acc1.y = fmaf(p, a1.y, acc1.y);
        acc1.z = fmaf(p, a1.z, acc1.z); acc1.w = fmaf(p, a1.w, acc1.w);

        xrow += D;
        a0 = b0; a1 = b1; b0 = c0; b1 = c1v;    // rotate
    }

    // ---- block-level merge of 4 wave partials via LDS ----
    __shared__ float lds_acc[WPB][D];
    __shared__ float lds_m[WPB], lds_l[WPB];
    *(float4*)(&lds_acc[wave][o0]) = acc0;
    *(float4*)(&lds_acc[wave][o1]) = acc1;
    if (lane == 0) { lds_m[wave] = m; lds_l[wave] = l; }
    __syncthreads();

    const float M  = fmaxf(fmaxf(lds_m[0], lds_m[1]), fmaxf(lds_m[2], lds_m[3]));
    const float e0 = __expf(lds_m[0] - M), e1 = __expf(lds_m[1] - M);
    const float e2 = __expf(lds_m[2] - M), e3 = __expf(lds_m[3] - M);
    const float L  = lds_l[0]*e0 + lds_l[1]*e1 + lds_l[2]*e2 + lds_l[3]*e3;

    const int d = tid * 2;   // 256 threads x 2 dims
    float p0 = e0*lds_acc[0][d]   + e1*lds_acc[1][d]   + e2*lds_acc[2][d]   + e3*lds_acc[3][d];
    float p1 = e0*lds_acc[0][d+1] + e1*lds_acc[1][d+1] + e2*lds_acc[2][d+1] + e3*lds_acc[3][d+1];
    *(float2*)(partial + (size_t)blk * D + d) = make_float2(p0, p1);
    if (tid == 0) { ml[2*blk] = M; ml[2*blk + 1] = L; }
}

// ---------------------------------------------------------------------------
// Kernel 2: combine the 128 block-partials per batch, normalize, write output.
// ---------------------------------------------------------------------------
__global__ __launch_bounds__(256)
void pool_pass2(const float* __restrict__ partial,
                const float* __restrict__ ml,
                float* __restrict__ out) {
    const int b   = blockIdx.x;
    const int tid = threadIdx.x;
    const float* mlb = ml + (size_t)b * BPB * 2;
    const float* pb  = partial + (size_t)b * BPB * D;

    float M = -INFINITY;
    #pragma unroll 8
    for (int i = 0; i < BPB; ++i) M = fmaxf(M, mlb[2*i]);

    const int d = tid * 2;
    float L = 0.f, acc0 = 0.f, acc1 = 0.f;
    #pragma unroll 4
    for (int i = 0; i < BPB; ++i) {
        const float wi = __expf(mlb[2*i] - M);
        L = fmaf(mlb[2*i + 1], wi, L);
        float2 v = *(const float2*)(pb + (size_t)i * D + d);
        acc0 = fmaf(wi, v.x, acc0);
        acc1 = fmaf(wi, v.y, acc1);
    }
    const float invL = 1.0f / L;
    out[(size_t)b * D + d]     = acc0 * invL;
    out[(size_t)b * D + d + 1] = acc1 * invL;
}

// ---------------------------------------------------------------------------
extern "C" void kernel_launch(void* const* d_in, const int* in_sizes, int n_in,
                              void* d_out, int out_size, void* d_ws, size_t ws_size,
                              hipStream_t stream) {
    const float* x    = (const float*)d_in[0];
    const float* q    = (const float*)d_in[1];
    const float* w    = (const float*)d_in[2];
    const float* bias = (const float*)d_in[3];
    float* ws      = (float*)d_ws;
    float* partial = ws + WS_PARTIAL;
    float* ml      = ws + WS_ML;
    float* out     = (float*)d_out;

    prep_kernel<<<1, 64, 0, stream>>>(q, w, bias, ws);
    pool_pass1<<<B * BPB, 256, 0, stream>>>(x, ws, partial, ml);
    pool_pass2<<<B, 256, 0, stream>>>(partial, ml, out);
}

// Round 6
// 380.728 us; speedup vs baseline: 1.0035x; 1.0035x over previous
//
#include <hip/hip_runtime.h>
#include <math.h>

#define EPS 1e-5f

constexpr int D   = 512;
constexpr int B   = 16;
constexpr int N   = 8192;
constexpr int BPB = 128;                      // blocks per batch
constexpr int WPB = 4;                        // waves per block (256 threads)
constexpr int ROWS_PER_BLOCK = N / BPB;       // 64
constexpr int ROWS_PER_WAVE  = ROWS_PER_BLOCK / WPB; // 16
constexpr int NPART = B * BPB;                // 2048 block-partials

// ws float layout (total ~4.03 MiB):
//   [0,512)              g[d] = qn[d]*w[d]/sqrt(D)
//   [512]                c1 = sum_d g[d]
//   [1024, 1024+NPART*D) block partial accumulators (2048*512 floats)
//   then NPART*2         (M, L) per block
constexpr size_t WS_PARTIAL = 1024;
constexpr size_t WS_ML      = WS_PARTIAL + (size_t)NPART * D;

// ---------------------------------------------------------------------------
// Kernel 0: layernorm the query, fold in ln_weight and 1/sqrt(D).
// One wave; lane j owns dims {4j..4j+3, 256+4j..256+4j+3}.
// score_n = inv_n * (sum_d g[d]*x[n,d] - mu_n * c1) + const; const cancels
// in softmax (it's sum_d qn[d]*b[d], row-independent).
// ---------------------------------------------------------------------------
__global__ void prep_kernel(const float* __restrict__ q,
                            const float* __restrict__ w,
                            const float* __restrict__ bias,
                            float* __restrict__ ws) {
    const int lane = threadIdx.x & 63;
    float4 q0 = *(const float4*)(q + 4 * lane);
    float4 q1 = *(const float4*)(q + 256 + 4 * lane);

    float s  = q0.x + q0.y + q0.z + q0.w + q1.x + q1.y + q1.z + q1.w;
    float ss = q0.x*q0.x + q0.y*q0.y + q0.z*q0.z + q0.w*q0.w
             + q1.x*q1.x + q1.y*q1.y + q1.z*q1.z + q1.w*q1.w;
    #pragma unroll
    for (int m = 1; m < 64; m <<= 1) {
        s  += __shfl_xor(s,  m);
        ss += __shfl_xor(ss, m);
    }
    const float mu  = s * (1.0f / 512.0f);
    const float var = ss * (1.0f / 512.0f) - mu * mu;
    const float inv = rsqrtf(var + EPS);
    const float scale = 0.044194173824159216f;   // 1/sqrt(512)

    float4 w0 = *(const float4*)(w + 4 * lane);
    float4 w1 = *(const float4*)(w + 256 + 4 * lane);
    float4 b0 = *(const float4*)(bias + 4 * lane);
    float4 b1 = *(const float4*)(bias + 256 + 4 * lane);

    float4 g0, g1;
    g0.x = ((q0.x - mu) * inv * w0.x + b0.x) * w0.x * scale;
    g0.y = ((q0.y - mu) * inv * w0.y + b0.y) * w0.y * scale;
    g0.z = ((q0.z - mu) * inv * w0.z + b0.z) * w0.z * scale;
    g0.w = ((q0.w - mu) * inv * w0.w + b0.w) * w0.w * scale;
    g1.x = ((q1.x - mu) * inv * w1.x + b1.x) * w1.x * scale;
    g1.y = ((q1.y - mu) * inv * w1.y + b1.y) * w1.y * scale;
    g1.z = ((q1.z - mu) * inv * w1.z + b1.z) * w1.z * scale;
    g1.w = ((q1.w - mu) * inv * w1.w + b1.w) * w1.w * scale;

    float c1 = g0.x + g0.y + g0.z + g0.w + g1.x + g1.y + g1.z + g1.w;
    #pragma unroll
    for (int m = 1; m < 64; m <<= 1) c1 += __shfl_xor(c1, m);

    *(float4*)(ws + 4 * lane)       = g0;
    *(float4*)(ws + 256 + 4 * lane) = g1;
    if (lane == 0) ws[512] = c1;
}

// ---------------------------------------------------------------------------
// Kernel 1: single-pass fused LN + score + online-softmax weighted pooling.
// One wave per row (64 lanes x 8 floats = full 2KB row in registers).
// Depth-2 rotating prefetch (rows r / r+1 / r+2 live) hides HBM latency
// within a wave; 4 blocks/CU (16 waves) gives TLP on top.
// __launch_bounds__(256,4): VGPR cap 128 — spill-proof margin for the
// unrolled/rotated schedule. Spill-freedom > occupancy here: 16 waves/CU
// already holds ~64KB of loads in flight vs ~2.5KB Little's-law need,
// while a single spilled float4 would add 32B/lane/row of scratch traffic
// to a BW-bound kernel. (R4 evidence: harness 1GiB fills run 6.6-6.8 TB/s
// = achievable ceiling; pass1 absent from top-5 so <158us, but dur_us
// budget suggests ~120us for our kernels vs 50us theory -> suspect spills
// at the previous 85-VGPR cap.)
// ---------------------------------------------------------------------------
__global__ __launch_bounds__(256, 4)
void pool_pass1(const float* __restrict__ x,
                const float* __restrict__ ws_g,
                float* __restrict__ partial,
                float* __restrict__ ml) {
    const int tid  = threadIdx.x;
    const int lane = tid & 63;
    const int wave = tid >> 6;
    const int blk      = blockIdx.x;        // 0..B*BPB-1
    const int b        = blk >> 7;          // / BPB
    const int blk_in_b = blk & (BPB - 1);

    const float c1 = ws_g[512];
    float4 g0 = *(const float4*)(ws_g + 4 * lane);
    float4 g1 = *(const float4*)(ws_g + 256 + 4 * lane);

    const float* xrow = x + ((size_t)b * N
                           + (size_t)blk_in_b * ROWS_PER_BLOCK
                           + (size_t)wave * ROWS_PER_WAVE) * D;
    const int o0 = 4 * lane;
    const int o1 = 256 + 4 * lane;

    float m = -INFINITY, l = 0.0f;
    float4 acc0 = {0.f, 0.f, 0.f, 0.f};
    float4 acc1 = {0.f, 0.f, 0.f, 0.f};

    // rotating buffers: a = row r (consumed), b = row r+1, c = row r+2 (loading)
    float4 a0 = *(const float4*)(xrow + o0);
    float4 a1 = *(const float4*)(xrow + o1);
    float4 b0 = *(const float4*)(xrow + D + o0);
    float4 b1 = *(const float4*)(xrow + D + o1);

    #pragma unroll
    for (int r = 0; r < ROWS_PER_WAVE; ++r) {
        float4 c0 = a0, c1v = a1;               // dummy init (tail iters)
        if (r + 2 < ROWS_PER_WAVE) {
            c0  = *(const float4*)(xrow + 2 * D + o0);
            c1v = *(const float4*)(xrow + 2 * D + o1);
        }

        float s  = a0.x + a0.y + a0.z + a0.w + a1.x + a1.y + a1.z + a1.w;
        float ss = a0.x*a0.x;
        ss = fmaf(a0.y, a0.y, ss); ss = fmaf(a0.z, a0.z, ss); ss = fmaf(a0.w, a0.w, ss);
        ss = fmaf(a1.x, a1.x, ss); ss = fmaf(a1.y, a1.y, ss);
        ss = fmaf(a1.z, a1.z, ss); ss = fmaf(a1.w, a1.w, ss);
        float gd = g0.x * a0.x;
        gd = fmaf(g0.y, a0.y, gd); gd = fmaf(g0.z, a0.z, gd); gd = fmaf(g0.w, a0.w, gd);
        gd = fmaf(g1.x, a1.x, gd); gd = fmaf(g1.y, a1.y, gd);
        gd = fmaf(g1.z, a1.z, gd); gd = fmaf(g1.w, a1.w, gd);

        #pragma unroll
        for (int msk = 1; msk < 64; msk <<= 1) {
            s  += __shfl_xor(s,  msk);
            ss += __shfl_xor(ss, msk);
            gd += __shfl_xor(gd, msk);
        }

        const float mu    = s * (1.0f / 512.0f);
        const float var   = ss * (1.0f / 512.0f) - mu * mu;
        const float inv   = rsqrtf(var + EPS);
        const float score = inv * fmaf(-mu, c1, gd);   // + const, cancels in softmax

        if (score > m) {               // wave-uniform branch
            const float f = __expf(m - score);   // m=-inf on first row -> f=0
            l *= f;
            acc0.x *= f; acc0.y *= f; acc0.z *= f; acc0.w *= f;
            acc1.x *= f; acc1.y *= f; acc1.z *= f; acc1.w *= f;
            m = score;
        }
        const float p = __expf(score - m);
        l += p;
        acc0.x = fmaf(p, a0.x, acc0.x); acc0.y = fmaf(p, a0.y, acc0.y);
        acc0.z = fmaf(p, a0.z, acc0.z); acc0.w = fmaf(p, a0.w, acc0.w);
        acc1.x = fmaf(p, a1.x, acc1.x); acc1.y = fmaf(p, a1.y, acc1.y);
        acc1.z = fmaf(p, a1.z, acc1.z); acc1.w = fmaf(p, a1.w, acc1.w);

        xrow += D;
        a0 = b0; a1 = b1; b0 = c0; b1 = c1v;    // rotate
    }

    // ---- block-level merge of 4 wave partials via LDS ----
    __shared__ float lds_acc[WPB][D];
    __shared__ float lds_m[WPB], lds_l[WPB];
    *(float4*)(&lds_acc[wave][o0]) = acc0;
    *(float4*)(&lds_acc[wave][o1]) = acc1;
    if (lane == 0) { lds_m[wave] = m; lds_l[wave] = l; }
    __syncthreads();

    const float M  = fmaxf(fmaxf(lds_m[0], lds_m[1]), fmaxf(lds_m[2], lds_m[3]));
    const float e0 = __expf(lds_m[0] - M), e1 = __expf(lds_m[1] - M);
    const float e2 = __expf(lds_m[2] - M), e3 = __expf(lds_m[3] - M);
    const float L  = lds_l[0]*e0 + lds_l[1]*e1 + lds_l[2]*e2 + lds_l[3]*e3;

    const int d = tid * 2;   // 256 threads x 2 dims
    float p0 = e0*lds_acc[0][d]   + e1*lds_acc[1][d]   + e2*lds_acc[2][d]   + e3*lds_acc[3][d];
    float p1 = e0*lds_acc[0][d+1] + e1*lds_acc[1][d+1] + e2*lds_acc[2][d+1] + e3*lds_acc[3][d+1];
    *(float2*)(partial + (size_t)blk * D + d) = make_float2(p0, p1);
    if (tid == 0) { ml[2*blk] = M; ml[2*blk + 1] = L; }
}

// ---------------------------------------------------------------------------
// Kernel 2: combine the 128 block-partials per batch, normalize, write output.
// ---------------------------------------------------------------------------
__global__ __launch_bounds__(256)
void pool_pass2(const float* __restrict__ partial,
                const float* __restrict__ ml,
                float* __restrict__ out) {
    const int b   = blockIdx.x;
    const int tid = threadIdx.x;
    const float* mlb = ml + (size_t)b * BPB * 2;
    const float* pb  = partial + (size_t)b * BPB * D;

    float M = -INFINITY;
    #pragma unroll 8
    for (int i = 0; i < BPB; ++i) M = fmaxf(M, mlb[2*i]);

    const int d = tid * 2;
    float L = 0.f, acc0 = 0.f, acc1 = 0.f;
    #pragma unroll 4
    for (int i = 0; i < BPB; ++i) {
        const float wi = __expf(mlb[2*i] - M);
        L = fmaf(mlb[2*i + 1], wi, L);
        float2 v = *(const float2*)(pb + (size_t)i * D + d);
        acc0 = fmaf(wi, v.x, acc0);
        acc1 = fmaf(wi, v.y, acc1);
    }
    const float invL = 1.0f / L;
    out[(size_t)b * D + d]     = acc0 * invL;
    out[(size_t)b * D + d + 1] = acc1 * invL;
}

// ---------------------------------------------------------------------------
extern "C" void kernel_launch(void* const* d_in, const int* in_sizes, int n_in,
                              void* d_out, int out_size, void* d_ws, size_t ws_size,
                              hipStream_t stream) {
    const float* x    = (const float*)d_in[0];
    const float* q    = (const float*)d_in[1];
    const float* w    = (const float*)d_in[2];
    const float* bias = (const float*)d_in[3];
    float* ws      = (float*)d_ws;
    float* partial = ws + WS_PARTIAL;
    float* ml      = ws + WS_ML;
    float* out     = (float*)d_out;

    prep_kernel<<<1, 64, 0, stream>>>(q, w, bias, ws);
    pool_pass1<<<B * BPB, 256, 0, stream>>>(x, ws, partial, ml);
    pool_pass2<<<B, 256, 0, stream>>>(partial, ml, out);
}